// Round 1
// baseline (59.726 us; speedup 1.0000x reference)
//
#include <hip/hip_runtime.h>
#include <math.h>

// Problem shape (fixed by setup_inputs): B=8, F=64, T=2048.
#define FCH 64
#define TLEN 2048

// Kernel 1: one block per (b,f). Reduce cos/sin sums over T, write
// sqrt(plv + eps) to ws[bf]. 256 threads x 8 floats = 2048.
__global__ __launch_bounds__(256) void plv_kernel(
    const float* __restrict__ phases, float* __restrict__ ws) {
    const int bf  = blockIdx.x;
    const int tid = threadIdx.x;
    const float4* p = (const float4*)(phases + (size_t)bf * TLEN);

    float cs = 0.0f, ss = 0.0f;
#pragma unroll
    for (int i = 0; i < 2; ++i) {
        // coalesced: lane t reads float4 index (i*256 + t)
        float4 v = p[i * 256 + tid];
        float s, c;
        sincosf(v.x, &s, &c); cs += c; ss += s;
        sincosf(v.y, &s, &c); cs += c; ss += s;
        sincosf(v.z, &s, &c); cs += c; ss += s;
        sincosf(v.w, &s, &c); cs += c; ss += s;
    }

    // wave64 butterfly reduce
#pragma unroll
    for (int off = 32; off > 0; off >>= 1) {
        cs += __shfl_down(cs, off);
        ss += __shfl_down(ss, off);
    }
    __shared__ float scs[4], sss[4];
    const int wave = tid >> 6;
    if ((tid & 63) == 0) { scs[wave] = cs; sss[wave] = ss; }
    __syncthreads();
    if (tid == 0) {
        float c = scs[0] + scs[1] + scs[2] + scs[3];
        float s = sss[0] + sss[1] + sss[2] + sss[3];
        float plv = sqrtf(c * c + s * s) * (1.0f / (float)TLEN);
        // triad_mag diagonal is identically 1 (triad == 0), so
        // sqrt(plv * diag + eps) == sqrt(plv + eps)
        ws[bf] = sqrtf(plv + 1e-12f);
    }
}

// Kernel 2: single block, one wave per b. Mean over F, clip, sigmoid
// hysteresis EMA, write out[b].
__global__ __launch_bounds__(512) void finish_kernel(
    const float* __restrict__ ws,
    const float* __restrict__ prev_coh,
    const float* __restrict__ prev_alpha,
    float* __restrict__ out, int B) {
    const int tid = threadIdx.x;
    const int b = tid >> 6;
    float s = (b < B) ? ws[tid] : 0.0f;
#pragma unroll
    for (int off = 32; off > 0; off >>= 1) s += __shfl_down(s, off);
    if ((tid & 63) == 0 && b < B) {
        float coh = s * (1.0f / (float)FCH);
        coh = fminf(fmaxf(coh, 0.0f), 1.0f);
        float pc = prev_coh[b];
        float v = coh - pc;
        float x = 8.0f * fabsf(v) - 1.5f;
        float sig = 1.0f / (1.0f + expf(-x));
        float target = 0.08f + (0.45f - 0.08f) * sig;
        float pa = prev_alpha[b];
        float alpha = pa + 0.12f * (target - pa);
        out[b] = alpha * coh + (1.0f - alpha) * pc;
    }
}

extern "C" void kernel_launch(void* const* d_in, const int* in_sizes, int n_in,
                              void* d_out, int out_size, void* d_ws, size_t ws_size,
                              hipStream_t stream) {
    const float* phases     = (const float*)d_in[0];
    const float* prev_coh   = (const float*)d_in[1];
    const float* prev_alpha = (const float*)d_in[2];
    float* out = (float*)d_out;
    float* ws  = (float*)d_ws;

    const int B = in_sizes[1];          // 8
    const int n_bf = B * FCH;           // 512

    plv_kernel<<<n_bf, 256, 0, stream>>>(phases, ws);
    finish_kernel<<<1, n_bf, 0, stream>>>(ws, prev_coh, prev_alpha, out, B);
}